// Round 12
// baseline (98.021 us; speedup 1.0000x reference)
//
#include <hip/hip_runtime.h>
#include <hip/hip_bf16.h>
#include <stdint.h>

#define Bsz 16
#define NHn 8
#define Dm  512
#define DHd 64
#define Ls  1024
// M = Bsz*Ls = 16384, N3 = 1536, K = 512

typedef __attribute__((ext_vector_type(8))) short bf16x8;
typedef __attribute__((ext_vector_type(4))) float f32x4;
typedef __attribute__((ext_vector_type(16))) float f32x16;
typedef __attribute__((ext_vector_type(4))) unsigned int u32x4;

#define MFMA16 __builtin_amdgcn_mfma_f32_16x16x32_bf16
#define MFMA32 __builtin_amdgcn_mfma_f32_32x32x16_bf16

// 0.125 (DH^-0.5) * log2(e): QK^T logits land pre-scaled for exp2
#define QSCALE 0.18033688011112042f

static __device__ __forceinline__ unsigned short f2bf(float f) {
    unsigned int u = __builtin_bit_cast(unsigned int, f);
    u += 0x7FFFu + ((u >> 16) & 1u);
    return (unsigned short)(u >> 16);
}

static __device__ __forceinline__ void gl2lds16(const void* g, void* l) {
    __builtin_amdgcn_global_load_lds(
        (const __attribute__((address_space(1))) unsigned int*)g,
        (__attribute__((address_space(3))) unsigned int*)l, 16, 0, 0);
}

// ---------------- pack_x: queries [B, D, L] f32 -> X [B*L, 512] bf16 ----------------
__global__ void __launch_bounds__(256) pack_x(const float* __restrict__ q,
                                              unsigned short* __restrict__ X) {
    __shared__ float tile[64][68];
    const int bid = blockIdx.x;
    const int b  = bid >> 7;
    const int dt = (bid >> 4) & 7;
    const int lt = bid & 15;
    const int t  = threadIdx.x;
    const int tr = t >> 4;
    const int tc = (t & 15) * 4;
    const float* src = q + ((size_t)b * Dm + dt * 64) * Ls + lt * 64;
#pragma unroll
    for (int p = 0; p < 4; ++p) {
        const int r = p * 16 + tr;
        const float4 v = *(const float4*)(src + (size_t)r * Ls + tc);
        tile[r][tc+0] = v.x; tile[r][tc+1] = v.y; tile[r][tc+2] = v.z; tile[r][tc+3] = v.w;
    }
    __syncthreads();
    unsigned short* dst = X + (size_t)(b * Ls + lt * 64) * Dm + dt * 64;
#pragma unroll
    for (int p = 0; p < 4; ++p) {
        const int lr = p * 16 + tr;
        ushort4 o;
        o.x = f2bf(tile[tc+0][lr]);
        o.y = f2bf(tile[tc+1][lr]);
        o.z = f2bf(tile[tc+2][lr]);
        o.w = f2bf(tile[tc+3][lr]);
        *(ushort4*)(dst + (size_t)lr * Dm + tc) = o;
    }
}

// ---------------- pack_w: [w_q ; w_mem] -> W [1536, 512] bf16 ----------------
__global__ void __launch_bounds__(256) pack_w(const float* __restrict__ wm,
                                              const float* __restrict__ wq,
                                              unsigned short* __restrict__ W) {
    const int i = (blockIdx.x * 256 + threadIdx.x) * 4;   // 1536*512 elems
    const int n = i >> 9;
    const int k = i & 511;
    const float* src = (n < 512) ? (wq + (size_t)n * 512 + k)
                                 : (wm + (size_t)(n - 512) * 512 + k);
    const float4 v = *(const float4*)src;
    ushort4 o;
    o.x = f2bf(v.x); o.y = f2bf(v.y); o.z = f2bf(v.z); o.w = f2bf(v.w);
    *(ushort4*)(W + i) = o;
}

// ---------------- gemm_qkv: [16384 x 1536] = X[16384,512] * W^T ----------------
// 512-thread / 8-wave, BK=32 variant of the verified 128x128 dbuf template:
// LDS 32 KB -> 4 blocks/CU (32 waves/CU). Wave grid 4x2, per-wave 32x64,
// counted vmcnt(2), 16 K-steps, swizzle key row&3 (4 chunks per 64B row).
// Masked kv rows are ZEROED in K and V so attn needs no mask logic
// (masked p = 2^0 = 1, corrected in the denominator).
__global__ void __launch_bounds__(512) gemm_qkv(const unsigned short* __restrict__ X,
                                                const unsigned short* __restrict__ W,
                                                const int* __restrict__ mask,
                                                unsigned short* __restrict__ Qb,
                                                unsigned short* __restrict__ Kb,
                                                unsigned short* __restrict__ VT) {
    __shared__ unsigned short Alds[2][128 * 32];
    __shared__ unsigned short Blds[2][128 * 32];
    // XCD swizzle: 1536 blocks % 8 == 0 -> each XCD gets 192 contiguous (16 mt x 12 nt)
    const int bid = (blockIdx.x & 7) * 192 + (blockIdx.x >> 3);
    const int nt = bid % 12, mt = bid / 12;
    const int m0 = mt * 128, n0 = nt * 128;
    const int t = threadIdx.x;
    const int w = t >> 6, lane = t & 63, g = lane >> 4, c = lane & 15;
    const int wm = w >> 1, wn = w & 1;                   // 4 x 2 wave grid

    // staging: A/B tiles are 512 16B chunks each; thread t stages chunk t of
    // each. chunk: row = t>>2, pc = t&3; source col chunk pre-swizzled
    // pc ^ (row&3); LDS dest linear (chunk t at byte 16t).
    const int srow = t >> 2;
    const int scol = ((t & 3) ^ (srow & 3)) * 8;         // in elements

    f32x4 acc[2][4];
#pragma unroll
    for (int i = 0; i < 2; ++i)
#pragma unroll
        for (int j = 0; j < 4; ++j) acc[i][j] = f32x4{0.f, 0.f, 0.f, 0.f};

#define STAGE(BUF, KT) do {                                                      \
        const int k0_ = (KT) * 32;                                               \
        gl2lds16(X + (size_t)(m0 + srow) * Dm + k0_ + scol,                      \
                 &Alds[BUF][w * 512]);                                           \
        gl2lds16(W + (size_t)(n0 + srow) * Dm + k0_ + scol,                      \
                 &Blds[BUF][w * 512]);                                           \
    } while (0)

#define KLOOP(SWAPPED) do {                                                      \
    for (int kt = 0; kt < 16; ++kt) {                                            \
        const int buf = kt & 1;                                                  \
        if (kt < 15) {                                                           \
            STAGE(buf ^ 1, kt + 1);                                              \
            asm volatile("s_waitcnt vmcnt(2)" ::: "memory");                     \
        } else {                                                                 \
            asm volatile("s_waitcnt vmcnt(0)" ::: "memory");                     \
        }                                                                        \
        __syncthreads();                                                         \
        const char* Ab = (const char*)&Alds[buf][0];                             \
        const char* Bb = (const char*)&Blds[buf][0];                             \
        bf16x8 av[2], bv[4];                                                     \
        _Pragma("unroll")                                                        \
        for (int mi = 0; mi < 2; ++mi) {                                         \
            const int R = wm * 32 + mi * 16 + c;                                 \
            av[mi] = *(const bf16x8*)(Ab + R * 64 +                              \
                      ((g * 16) ^ ((R & 3) << 4)));                              \
        }                                                                        \
        _Pragma("unroll")                                                        \
        for (int nj = 0; nj < 4; ++nj) {                                         \
            const int R = wn * 64 + nj * 16 + c;                                 \
            bv[nj] = *(const bf16x8*)(Bb + R * 64 +                              \
                      ((g * 16) ^ ((R & 3) << 4)));                              \
        }                                                                        \
        _Pragma("unroll")                                                        \
        for (int mi = 0; mi < 2; ++mi)                                           \
            _Pragma("unroll")                                                    \
            for (int nj = 0; nj < 4; ++nj)                                       \
                acc[mi][nj] = (SWAPPED)                                          \
                    ? MFMA16(bv[nj], av[mi], acc[mi][nj], 0, 0, 0)               \
                    : MFMA16(av[mi], bv[nj], acc[mi][nj], 0, 0, 0);              \
        __syncthreads();                                                         \
    }                                                                            \
} while (0)

    STAGE(0, 0);
    const int bq = m0 >> 10;                       // tiles don't straddle batches

    if (n0 < 1024) {                               // Q or K: swapped operands
        KLOOP(1);
        // C rows = n (g*4+r), cols = m (c): all 4 regs share one l
        const int m_loc = (m0 & 1023) + wm * 32 + c;
        const int hbase = ((n0 < 512) ? n0 : (n0 - 512)) >> 6;
        const bool isK = (n0 >= 512);
        unsigned short* dstbase = isK ? Kb : Qb;
        const float scale = isK ? 1.0f : QSCALE;
        unsigned short* base = dstbase + ((size_t)(bq * NHn + hbase + wn) * Ls) * DHd;
        const int dh0 = g * 4;
        int mk[2];
#pragma unroll
        for (int mi = 0; mi < 2; ++mi)
            mk[mi] = isK ? mask[bq * Ls + m_loc + mi * 16] : 1;
#pragma unroll
        for (int nj = 0; nj < 4; ++nj) {
#pragma unroll
            for (int mi = 0; mi < 2; ++mi) {
                ushort4 o;
                if (mk[mi]) {
                    o.x = f2bf(acc[mi][nj][0] * scale);
                    o.y = f2bf(acc[mi][nj][1] * scale);
                    o.z = f2bf(acc[mi][nj][2] * scale);
                    o.w = f2bf(acc[mi][nj][3] * scale);
                } else {
                    o.x = 0; o.y = 0; o.z = 0; o.w = 0;
                }
                *(ushort4*)(base + (size_t)(m_loc + mi * 16) * DHd + nj * 16 + dh0) = o;
            }
        }
    } else {                                       // V: natural operands, VT layout
        KLOOP(0);
        // C rows = m (g*4+r), cols = n (c): store 4 consecutive l
        const int m_loc = (m0 & 1023) + wm * 32 + g * 4;
        const int hbase = (n0 - 1024) >> 6;
        unsigned short* base = VT + ((size_t)(bq * NHn + hbase + wn) * DHd) * Ls;
        int4 mv[2];
#pragma unroll
        for (int mi = 0; mi < 2; ++mi)
            mv[mi] = *(const int4*)(mask + bq * Ls + m_loc + mi * 16);
#pragma unroll
        for (int nj = 0; nj < 4; ++nj) {
            const int dh = nj * 16 + c;
#pragma unroll
            for (int mi = 0; mi < 2; ++mi) {
                ushort4 o;
                o.x = mv[mi].x ? f2bf(acc[mi][nj][0]) : (unsigned short)0;
                o.y = mv[mi].y ? f2bf(acc[mi][nj][1]) : (unsigned short)0;
                o.z = mv[mi].z ? f2bf(acc[mi][nj][2]) : (unsigned short)0;
                o.w = mv[mi].w ? f2bf(acc[mi][nj][3]) : (unsigned short)0;
                *(ushort4*)(base + (size_t)dh * Ls + m_loc + mi * 16) = o;
            }
        }
    }
#undef KLOOP
#undef STAGE
}

// ---------------- attn: flash, 8 waves x 32 q-rows (QBLK=256), 32x32 MFMA ----------------
// Verified R9/R11 skeleton EXACTLY (2 buffers, 64-kv tiles, vmcnt(0), STAGE after
// barrier) + s_setprio hints around the MFMA clusters. S^T = mfma32(K, Q);
// softmax in-lane, exp2-domain, no max tracking; mask pre-folded into K/V
// (zeroed rows): masked p = 1, corrected by lsum -= nmask. P transposed via
// cvt_pk_bf16 + permlane32_swap.
__global__ void __launch_bounds__(512) attn(const unsigned short* __restrict__ Qb,
                                            const unsigned short* __restrict__ Kb,
                                            const unsigned short* __restrict__ VT,
                                            const int* __restrict__ mask,
                                            float* __restrict__ out) {
    __shared__ unsigned short Klds[2][4096];   // [64 kv][64 dh] bf16, chunk-swizzled
    __shared__ unsigned short Vlds[2][4096];   // [64 dh][64 kv] bf16, chunk-swizzled

    const int bid = blockIdx.x;
    // XCD-aware swizzle: 4 q-blocks of one bh land on one XCD (512 % 8 == 0)
    const int xcd = bid & 7;
    const int idx = bid >> 3;
    const int qblk = idx & 3;
    const int bh = ((idx >> 2) << 3) | xcd;
    const int b = bh >> 3, h = bh & 7;
    const int t = threadIdx.x, w = t >> 6, lane = t & 63;
    const int c5 = lane & 31, hi = lane >> 5;
    const int sw = (c5 & 7) << 4;

    const unsigned short* Qh = Qb + (size_t)bh * (Ls * DHd);
    const unsigned short* Kh = Kb + (size_t)bh * (Ls * DHd);
    const unsigned short* Vh = VT + (size_t)bh * (DHd * Ls);
    const int q = qblk * 256 + w * 32 + c5;

    // per-wave masked-count (one-time): lsum correction for p=1 at masked kv
    float fnmask;
    {
        int s = 0;
        const int4* mp = (const int4*)(mask + b * Ls);
#pragma unroll
        for (int j = 0; j < 4; ++j) {
            const int4 mv = mp[j * 64 + lane];
            s += (mv.x + mv.y) + (mv.z + mv.w);
        }
#pragma unroll
        for (int off = 1; off < 64; off <<= 1) s += __shfl_xor(s, off);
        fnmask = (float)(Ls - s);                  // number of masked positions
    }

    // Q fragments (B-operand of mfma32: lane holds Q[q=c5][dh = 16ks + 8hi + j])
    bf16x8 qf[4];
#pragma unroll
    for (int ks = 0; ks < 4; ++ks)
        qf[ks] = *(const bf16x8*)(Qh + (size_t)q * DHd + ks * 16 + hi * 8);

    // staging: 512 16B chunks per tile per matrix; thread t handles chunk t.
    // LDS linear dest (global_load_lds), global source pre-swizzled (rule 21).
    const int r0 = t >> 3, c0b = (t & 7) << 4;
    const int ksrc0 = r0 * 128  + (c0b ^ ((r0 & 7) << 4));
    const int vsrc0 = r0 * 2048 + (c0b ^ ((r0 & 7) << 4));

#define STAGE(BUF, KV0) do {                                          \
        const char* Kc = (const char*)Kh + (size_t)(KV0) * 128;       \
        const char* Vc = (const char*)Vh + (size_t)(KV0) * 2;         \
        gl2lds16(Kc + ksrc0, &Klds[BUF][w * 512]);                    \
        gl2lds16(Vc + vsrc0, &Vlds[BUF][w * 512]);                    \
    } while (0)

    STAGE(0, 0);

    float lsum = 0.f;
    f32x16 oacc0, oacc1;
#pragma unroll
    for (int i = 0; i < 16; ++i) { oacc0[i] = 0.f; oacc1[i] = 0.f; }

    for (int it = 0; it < 16; ++it) {
        const int kv0 = it * 64;
        const int buf = it & 1;
        asm volatile("s_waitcnt vmcnt(0)" ::: "memory");
        __syncthreads();
        if (it < 15) STAGE(buf ^ 1, kv0 + 64);

        f32x16 acc0, acc1;
#pragma unroll
        for (int i = 0; i < 16; ++i) { acc0[i] = 0.f; acc1[i] = 0.f; }

        // S^T = K * Q^T : A = K[kv row][dh k], B = Q (in reg)
        const char* Kbase = (const char*)&Klds[buf][0];
        __builtin_amdgcn_s_setprio(1);
#pragma unroll
        for (int ks = 0; ks < 4; ++ks) {
            const bf16x8 k0 = *(const bf16x8*)(Kbase + c5 * 128 + ((ks * 32 + hi * 16) ^ sw));
            acc0 = MFMA32(k0, qf[ks], acc0, 0, 0, 0);
            const bf16x8 k1 = *(const bf16x8*)(Kbase + (32 + c5) * 128 + ((ks * 32 + hi * 16) ^ sw));
            acc1 = MFMA32(k1, qf[ks], acc1, 0, 0, 0);
        }
        __builtin_amdgcn_s_setprio(0);

        // in-lane softmax (exp2 domain, no max, no mask) + pack P pairs to bf16
        unsigned pk0[8], pk1[8];
#pragma unroll
        for (int u = 0; u < 4; ++u) {
            float p0 = __builtin_amdgcn_exp2f(acc0[4*u+0]);
            float p1 = __builtin_amdgcn_exp2f(acc0[4*u+1]);
            float p2 = __builtin_amdgcn_exp2f(acc0[4*u+2]);
            float p3 = __builtin_amdgcn_exp2f(acc0[4*u+3]);
            lsum += (p0 + p1) + (p2 + p3);
            asm("v_cvt_pk_bf16_f32 %0, %1, %2" : "=v"(pk0[2*u+0]) : "v"(p0), "v"(p1));
            asm("v_cvt_pk_bf16_f32 %0, %1, %2" : "=v"(pk0[2*u+1]) : "v"(p2), "v"(p3));
            float s0 = __builtin_amdgcn_exp2f(acc1[4*u+0]);
            float s1 = __builtin_amdgcn_exp2f(acc1[4*u+1]);
            float s2 = __builtin_amdgcn_exp2f(acc1[4*u+2]);
            float s3 = __builtin_amdgcn_exp2f(acc1[4*u+3]);
            lsum += (s0 + s1) + (s2 + s3);
            asm("v_cvt_pk_bf16_f32 %0, %1, %2" : "=v"(pk1[2*u+0]) : "v"(s0), "v"(s1));
            asm("v_cvt_pk_bf16_f32 %0, %1, %2" : "=v"(pk1[2*u+1]) : "v"(s2), "v"(s3));
        }

        // PV: B-frag[s] built from pk via permlane32_swap; A = V^T from LDS
        const char* Vbase = (const char*)&Vlds[buf][0];
#define PV_STEP(S, PK) do {                                                         \
            unsigned a0 = PK[2 * (2 * ((S) & 1) + 0) + 0];                          \
            unsigned a1 = PK[2 * (2 * ((S) & 1) + 0) + 1];                          \
            unsigned b0 = PK[2 * (2 * ((S) & 1) + 1) + 0];                          \
            unsigned b1 = PK[2 * (2 * ((S) & 1) + 1) + 1];                          \
            asm("v_permlane32_swap_b32 %0, %1" : "+v"(a0), "+v"(b0));               \
            asm("v_permlane32_swap_b32 %0, %1" : "+v"(a1), "+v"(b1));               \
            const u32x4 fw = {a0, a1, b0, b1};                                      \
            const bf16x8 pf = __builtin_bit_cast(bf16x8, fw);                       \
            const bf16x8 v0 = *(const bf16x8*)(Vbase + c5 * 128 + (((S) * 32 + hi * 16) ^ sw)); \
            oacc0 = MFMA32(v0, pf, oacc0, 0, 0, 0);                                 \
            const bf16x8 v1 = *(const bf16x8*)(Vbase + (32 + c5) * 128 + (((S) * 32 + hi * 16) ^ sw)); \
            oacc1 = MFMA32(v1, pf, oacc1, 0, 0, 0);                                 \
        } while (0)
        __builtin_amdgcn_s_setprio(1);
        PV_STEP(0, pk0);
        PV_STEP(1, pk0);
        PV_STEP(2, pk1);
        PV_STEP(3, pk1);
        __builtin_amdgcn_s_setprio(0);
#undef PV_STEP
    }

    // epilogue: combine hi-halves, subtract masked count, divide, store O^T[dh][q]
    lsum += __shfl_xor(lsum, 32);
    lsum -= fnmask;
    const float rinv = __builtin_amdgcn_rcpf(lsum);
    float* ob = out + (size_t)(b * Dm + h * DHd) * Ls + q;
#pragma unroll
    for (int reg = 0; reg < 16; ++reg) {
        const int dh = (reg & 3) + 8 * (reg >> 2) + 4 * hi;
        ob[(size_t)dh * Ls] = oacc0[reg] * rinv;
    }
#pragma unroll
    for (int reg = 0; reg < 16; ++reg) {
        const int dh = 32 + (reg & 3) + 8 * (reg >> 2) + 4 * hi;
        ob[(size_t)dh * Ls] = oacc1[reg] * rinv;
    }
#undef STAGE
}

extern "C" void kernel_launch(void* const* d_in, const int* in_sizes, int n_in,
                              void* d_out, int out_size, void* d_ws, size_t ws_size,
                              hipStream_t stream) {
    const float* queries = (const float*)d_in[0];
    const int*   mask    = (const int*)d_in[1];
    const float* w_mem   = (const float*)d_in[2];
    const float* w_q     = (const float*)d_in[3];
    float* out = (float*)d_out;

    char* ws = (char*)d_ws;
    // layout: X 16 MB | W 1.5 MB | Q 16 MB | K 16 MB | VT 16 MB  (~69 MB)
    unsigned short* X  = (unsigned short*)(ws);
    unsigned short* W  = (unsigned short*)(ws + 16777216);
    unsigned short* Qb = (unsigned short*)(ws + 18350080);
    unsigned short* Kb = (unsigned short*)(ws + 35127296);
    unsigned short* VT = (unsigned short*)(ws + 51904512);
    if (ws_size < 68681728) return;  // fail loudly (output stays poisoned)

    pack_x<<<dim3(2048), dim3(256), 0, stream>>>(queries, X);
    pack_w<<<dim3(768),  dim3(256), 0, stream>>>(w_mem, w_q, W);
    gemm_qkv<<<dim3(1536), dim3(512), 0, stream>>>(X, W, mask, Qb, Kb, VT);
    attn<<<dim3(512), dim3(512), 0, stream>>>(Qb, Kb, VT, mask, out);
}

// Round 13
// 91.146 us; speedup vs baseline: 1.0754x; 1.0754x over previous
//
#include <hip/hip_runtime.h>
#include <hip/hip_bf16.h>
#include <stdint.h>

#define Bsz 16
#define NHn 8
#define Dm  512
#define DHd 64
#define Ls  1024
// M = Bsz*Ls = 16384, N3 = 1536, K = 512

typedef __attribute__((ext_vector_type(8))) short bf16x8;
typedef __attribute__((ext_vector_type(4))) float f32x4;
typedef __attribute__((ext_vector_type(16))) float f32x16;
typedef __attribute__((ext_vector_type(4))) unsigned int u32x4;

#define MFMA16 __builtin_amdgcn_mfma_f32_16x16x32_bf16
#define MFMA32 __builtin_amdgcn_mfma_f32_32x32x16_bf16

// 0.125 (DH^-0.5) * log2(e): QK^T logits land pre-scaled for exp2
#define QSCALE 0.18033688011112042f

static __device__ __forceinline__ unsigned short f2bf(float f) {
    unsigned int u = __builtin_bit_cast(unsigned int, f);
    u += 0x7FFFu + ((u >> 16) & 1u);
    return (unsigned short)(u >> 16);
}

static __device__ __forceinline__ void gl2lds16(const void* g, void* l) {
    __builtin_amdgcn_global_load_lds(
        (const __attribute__((address_space(1))) unsigned int*)g,
        (__attribute__((address_space(3))) unsigned int*)l, 16, 0, 0);
}

// ------- pack_xw: fused pack_x (blocks 0..2047) + pack_w (blocks 2048..2815) -------
__global__ void __launch_bounds__(256) pack_xw(const float* __restrict__ q,
                                               const float* __restrict__ wm,
                                               const float* __restrict__ wq,
                                               unsigned short* __restrict__ X,
                                               unsigned short* __restrict__ W) {
    __shared__ float tile[64][68];
    const int t = threadIdx.x;
    if (blockIdx.x < 2048) {
        // pack_x: queries [B, D, L] f32 -> X [B*L, 512] bf16
        const int bid = blockIdx.x;
        const int b  = bid >> 7;
        const int dt = (bid >> 4) & 7;
        const int lt = bid & 15;
        const int tr = t >> 4;
        const int tc = (t & 15) * 4;
        const float* src = q + ((size_t)b * Dm + dt * 64) * Ls + lt * 64;
#pragma unroll
        for (int p = 0; p < 4; ++p) {
            const int r = p * 16 + tr;
            const float4 v = *(const float4*)(src + (size_t)r * Ls + tc);
            tile[r][tc+0] = v.x; tile[r][tc+1] = v.y; tile[r][tc+2] = v.z; tile[r][tc+3] = v.w;
        }
        __syncthreads();
        unsigned short* dst = X + (size_t)(b * Ls + lt * 64) * Dm + dt * 64;
#pragma unroll
        for (int p = 0; p < 4; ++p) {
            const int lr = p * 16 + tr;
            ushort4 o;
            o.x = f2bf(tile[tc+0][lr]);
            o.y = f2bf(tile[tc+1][lr]);
            o.z = f2bf(tile[tc+2][lr]);
            o.w = f2bf(tile[tc+3][lr]);
            *(ushort4*)(dst + (size_t)lr * Dm + tc) = o;
        }
    } else {
        // pack_w: [w_q ; w_mem] -> W [1536, 512] bf16
        const int i = ((blockIdx.x - 2048) * 256 + t) * 4;   // 1536*512 elems
        const int n = i >> 9;
        const int k = i & 511;
        const float* src = (n < 512) ? (wq + (size_t)n * 512 + k)
                                     : (wm + (size_t)(n - 512) * 512 + k);
        const float4 v = *(const float4*)src;
        ushort4 o;
        o.x = f2bf(v.x); o.y = f2bf(v.y); o.z = f2bf(v.z); o.w = f2bf(v.w);
        *(ushort4*)(W + i) = o;
    }
}

// ---------------- gemm_qkv: [16384 x 1536] = X[16384,512] * W^T ----------------
// R11-verified 512-thread / 8-wave 128x128x64 dbuf template (wave grid 4x2,
// per-wave 32x64, counted vmcnt(4)). Each block now computes TWO output tiles
// over the same A panel (Q then K, or two V tiles -- same SWAPPED class), with
// a vmcnt(0) drain + re-prologue between them. T2 swizzle, XCD-chunked bid
// swizzle. Masked kv rows are ZEROED in K and V so attn needs no mask logic
// (masked p = 2^0 = 1, corrected in the denominator).
__global__ void __launch_bounds__(512) gemm_qkv(const unsigned short* __restrict__ X,
                                                const unsigned short* __restrict__ W,
                                                const int* __restrict__ mask,
                                                unsigned short* __restrict__ Qb,
                                                unsigned short* __restrict__ Kb,
                                                unsigned short* __restrict__ VT) {
    __shared__ unsigned short Alds[2][128 * 64];
    __shared__ unsigned short Blds[2][128 * 64];
    // XCD swizzle: 768 blocks % 8 == 0 -> each XCD gets 96 contiguous pair-ids
    const int bid = (blockIdx.x & 7) * 96 + (blockIdx.x >> 3);
    const int pc = bid % 6, mt = bid / 6;
    const int m0 = mt * 128;
    const int t = threadIdx.x;
    const int w = t >> 6, lane = t & 63, g = lane >> 4, c = lane & 15;
    const int wm = w >> 1, wn = w & 1;                   // 4 x 2 wave grid

    // staging: A/B tiles are 1024 16B chunks each; thread t stages chunks t and
    // t+512 of each. chunk ci: row = ci>>3, pck = ci&7; source col chunk pre-
    // swizzled pck ^ (row&7) (rows 64 apart share row&7, so one scol serves both).
    const int srow = t >> 3;
    const int scol = (((t & 7) ^ (srow & 7))) * 8;       // in elements

    int n0;                                              // runtime per sub-tile
    f32x4 acc[2][4];

#define STAGE(BUF, KT) do {                                                      \
        const int k0_ = (KT) * 64;                                               \
        gl2lds16(X + (size_t)(m0 + srow) * Dm + k0_ + scol,                      \
                 &Alds[BUF][w * 512]);                                           \
        gl2lds16(X + (size_t)(m0 + 64 + srow) * Dm + k0_ + scol,                 \
                 &Alds[BUF][4096 + w * 512]);                                    \
        gl2lds16(W + (size_t)(n0 + srow) * Dm + k0_ + scol,                      \
                 &Blds[BUF][w * 512]);                                           \
        gl2lds16(W + (size_t)(n0 + 64 + srow) * Dm + k0_ + scol,                 \
                 &Blds[BUF][4096 + w * 512]);                                    \
    } while (0)

#define KLOOP(SWAPPED) do {                                                      \
    for (int kt = 0; kt < 8; ++kt) {                                             \
        const int buf = kt & 1;                                                  \
        if (kt < 7) {                                                            \
            STAGE(buf ^ 1, kt + 1);                                              \
            asm volatile("s_waitcnt vmcnt(4)" ::: "memory");                     \
        } else {                                                                 \
            asm volatile("s_waitcnt vmcnt(0)" ::: "memory");                     \
        }                                                                        \
        __syncthreads();                                                         \
        const char* Ab = (const char*)&Alds[buf][0];                             \
        const char* Bb = (const char*)&Blds[buf][0];                             \
        _Pragma("unroll")                                                        \
        for (int kk = 0; kk < 2; ++kk) {                                         \
            bf16x8 av[2], bv[4];                                                 \
            _Pragma("unroll")                                                    \
            for (int mi = 0; mi < 2; ++mi) {                                     \
                const int R = wm * 32 + mi * 16 + c;                             \
                av[mi] = *(const bf16x8*)(Ab + R * 128 +                         \
                          ((kk * 64 + g * 16) ^ ((R & 7) << 4)));                \
            }                                                                    \
            _Pragma("unroll")                                                    \
            for (int nj = 0; nj < 4; ++nj) {                                     \
                const int R = wn * 64 + nj * 16 + c;                             \
                bv[nj] = *(const bf16x8*)(Bb + R * 128 +                         \
                          ((kk * 64 + g * 16) ^ ((R & 7) << 4)));                \
            }                                                                    \
            _Pragma("unroll")                                                    \
            for (int mi = 0; mi < 2; ++mi)                                       \
                _Pragma("unroll")                                                \
                for (int nj = 0; nj < 4; ++nj)                                   \
                    acc[mi][nj] = (SWAPPED)                                      \
                        ? MFMA16(bv[nj], av[mi], acc[mi][nj], 0, 0, 0)           \
                        : MFMA16(av[mi], bv[nj], acc[mi][nj], 0, 0, 0);          \
        }                                                                        \
        __syncthreads();                                                         \
    }                                                                            \
} while (0)

#define ACC_RESET() do {                                                         \
        _Pragma("unroll")                                                        \
        for (int i_ = 0; i_ < 2; ++i_)                                           \
            _Pragma("unroll")                                                    \
            for (int j_ = 0; j_ < 4; ++j_)                                       \
                acc[i_][j_] = f32x4{0.f, 0.f, 0.f, 0.f};                         \
    } while (0)

    const int bq = m0 >> 10;                       // tiles don't straddle batches

#define EPI_QK() do {                                                            \
        const int m_loc = (m0 & 1023) + wm * 32 + c;                             \
        const int hbase = ((n0 < 512) ? n0 : (n0 - 512)) >> 6;                   \
        const bool isK = (n0 >= 512);                                            \
        unsigned short* dstbase = isK ? Kb : Qb;                                 \
        const float scale = isK ? 1.0f : QSCALE;                                 \
        unsigned short* base = dstbase +                                         \
            ((size_t)(bq * NHn + hbase + wn) * Ls) * DHd;                        \
        const int dh0 = g * 4;                                                   \
        int mk[2];                                                               \
        _Pragma("unroll")                                                        \
        for (int mi = 0; mi < 2; ++mi)                                           \
            mk[mi] = isK ? mask[bq * Ls + m_loc + mi * 16] : 1;                  \
        _Pragma("unroll")                                                        \
        for (int nj = 0; nj < 4; ++nj) {                                         \
            _Pragma("unroll")                                                    \
            for (int mi = 0; mi < 2; ++mi) {                                     \
                ushort4 o;                                                       \
                if (mk[mi]) {                                                    \
                    o.x = f2bf(acc[mi][nj][0] * scale);                          \
                    o.y = f2bf(acc[mi][nj][1] * scale);                          \
                    o.z = f2bf(acc[mi][nj][2] * scale);                          \
                    o.w = f2bf(acc[mi][nj][3] * scale);                          \
                } else {                                                         \
                    o.x = 0; o.y = 0; o.z = 0; o.w = 0;                          \
                }                                                                \
                *(ushort4*)(base + (size_t)(m_loc + mi * 16) * DHd               \
                            + nj * 16 + dh0) = o;                                \
            }                                                                    \
        }                                                                        \
    } while (0)

#define EPI_V() do {                                                             \
        const int m_loc = (m0 & 1023) + wm * 32 + g * 4;                         \
        const int hbase = (n0 - 1024) >> 6;                                      \
        unsigned short* base = VT +                                              \
            ((size_t)(bq * NHn + hbase + wn) * DHd) * Ls;                        \
        int4 mv[2];                                                              \
        _Pragma("unroll")                                                        \
        for (int mi = 0; mi < 2; ++mi)                                           \
            mv[mi] = *(const int4*)(mask + bq * Ls + m_loc + mi * 16);           \
        _Pragma("unroll")                                                        \
        for (int nj = 0; nj < 4; ++nj) {                                         \
            const int dh = nj * 16 + c;                                          \
            _Pragma("unroll")                                                    \
            for (int mi = 0; mi < 2; ++mi) {                                     \
                ushort4 o;                                                       \
                o.x = mv[mi].x ? f2bf(acc[mi][nj][0]) : (unsigned short)0;       \
                o.y = mv[mi].y ? f2bf(acc[mi][nj][1]) : (unsigned short)0;       \
                o.z = mv[mi].z ? f2bf(acc[mi][nj][2]) : (unsigned short)0;       \
                o.w = mv[mi].w ? f2bf(acc[mi][nj][3]) : (unsigned short)0;       \
                *(ushort4*)(base + (size_t)dh * Ls + m_loc + mi * 16) = o;       \
            }                                                                    \
        }                                                                        \
    } while (0)

    if (pc < 4) {                                  // Q tile then K tile, SWAPPED=1
#pragma unroll
        for (int s = 0; s < 2; ++s) {
            n0 = (pc + 4 * s) * 128;               // s=0: Q (0..511), s=1: K (512..1023)
            ACC_RESET();
            STAGE(0, 0);
            KLOOP(1);
            EPI_QK();
            if (s == 0) { asm volatile("s_waitcnt vmcnt(0)" ::: "memory"); }
        }
    } else {                                       // two V tiles, SWAPPED=0
#pragma unroll
        for (int s = 0; s < 2; ++s) {
            n0 = (4 + pc + 2 * s) * 128;           // pc=4: nt 8,10; pc=5: nt 9,11
            ACC_RESET();
            STAGE(0, 0);
            KLOOP(0);
            EPI_V();
            if (s == 0) { asm volatile("s_waitcnt vmcnt(0)" ::: "memory"); }
        }
    }
#undef EPI_V
#undef EPI_QK
#undef ACC_RESET
#undef KLOOP
#undef STAGE
}

// ---------------- attn: flash, 8 waves x 32 q-rows (QBLK=256), 32x32 MFMA ----------------
// Verified R9/R11 skeleton EXACTLY (2 buffers, 64-kv tiles, vmcnt(0), STAGE after
// barrier) + s_setprio hints around the MFMA clusters. S^T = mfma32(K, Q);
// softmax in-lane, exp2-domain, no max tracking; mask pre-folded into K/V
// (zeroed rows): masked p = 1, corrected by lsum -= nmask. P transposed via
// cvt_pk_bf16 + permlane32_swap.
__global__ void __launch_bounds__(512) attn(const unsigned short* __restrict__ Qb,
                                            const unsigned short* __restrict__ Kb,
                                            const unsigned short* __restrict__ VT,
                                            const int* __restrict__ mask,
                                            float* __restrict__ out) {
    __shared__ unsigned short Klds[2][4096];   // [64 kv][64 dh] bf16, chunk-swizzled
    __shared__ unsigned short Vlds[2][4096];   // [64 dh][64 kv] bf16, chunk-swizzled

    const int bid = blockIdx.x;
    // XCD-aware swizzle: 4 q-blocks of one bh land on one XCD (512 % 8 == 0)
    const int xcd = bid & 7;
    const int idx = bid >> 3;
    const int qblk = idx & 3;
    const int bh = ((idx >> 2) << 3) | xcd;
    const int b = bh >> 3, h = bh & 7;
    const int t = threadIdx.x, w = t >> 6, lane = t & 63;
    const int c5 = lane & 31, hi = lane >> 5;
    const int sw = (c5 & 7) << 4;

    const unsigned short* Qh = Qb + (size_t)bh * (Ls * DHd);
    const unsigned short* Kh = Kb + (size_t)bh * (Ls * DHd);
    const unsigned short* Vh = VT + (size_t)bh * (DHd * Ls);
    const int q = qblk * 256 + w * 32 + c5;

    // per-wave masked-count (one-time): lsum correction for p=1 at masked kv
    float fnmask;
    {
        int s = 0;
        const int4* mp = (const int4*)(mask + b * Ls);
#pragma unroll
        for (int j = 0; j < 4; ++j) {
            const int4 mv = mp[j * 64 + lane];
            s += (mv.x + mv.y) + (mv.z + mv.w);
        }
#pragma unroll
        for (int off = 1; off < 64; off <<= 1) s += __shfl_xor(s, off);
        fnmask = (float)(Ls - s);                  // number of masked positions
    }

    // Q fragments (B-operand of mfma32: lane holds Q[q=c5][dh = 16ks + 8hi + j])
    bf16x8 qf[4];
#pragma unroll
    for (int ks = 0; ks < 4; ++ks)
        qf[ks] = *(const bf16x8*)(Qh + (size_t)q * DHd + ks * 16 + hi * 8);

    // staging: 512 16B chunks per tile per matrix; thread t handles chunk t.
    // LDS linear dest (global_load_lds), global source pre-swizzled (rule 21).
    const int r0 = t >> 3, c0b = (t & 7) << 4;
    const int ksrc0 = r0 * 128  + (c0b ^ ((r0 & 7) << 4));
    const int vsrc0 = r0 * 2048 + (c0b ^ ((r0 & 7) << 4));

#define STAGE(BUF, KV0) do {                                          \
        const char* Kc = (const char*)Kh + (size_t)(KV0) * 128;       \
        const char* Vc = (const char*)Vh + (size_t)(KV0) * 2;         \
        gl2lds16(Kc + ksrc0, &Klds[BUF][w * 512]);                    \
        gl2lds16(Vc + vsrc0, &Vlds[BUF][w * 512]);                    \
    } while (0)

    STAGE(0, 0);

    float lsum = 0.f;
    f32x16 oacc0, oacc1;
#pragma unroll
    for (int i = 0; i < 16; ++i) { oacc0[i] = 0.f; oacc1[i] = 0.f; }

    for (int it = 0; it < 16; ++it) {
        const int kv0 = it * 64;
        const int buf = it & 1;
        asm volatile("s_waitcnt vmcnt(0)" ::: "memory");
        __syncthreads();
        if (it < 15) STAGE(buf ^ 1, kv0 + 64);

        f32x16 acc0, acc1;
#pragma unroll
        for (int i = 0; i < 16; ++i) { acc0[i] = 0.f; acc1[i] = 0.f; }

        // S^T = K * Q^T : A = K[kv row][dh k], B = Q (in reg)
        const char* Kbase = (const char*)&Klds[buf][0];
        __builtin_amdgcn_s_setprio(1);
#pragma unroll
        for (int ks = 0; ks < 4; ++ks) {
            const bf16x8 k0 = *(const bf16x8*)(Kbase + c5 * 128 + ((ks * 32 + hi * 16) ^ sw));
            acc0 = MFMA32(k0, qf[ks], acc0, 0, 0, 0);
            const bf16x8 k1 = *(const bf16x8*)(Kbase + (32 + c5) * 128 + ((ks * 32 + hi * 16) ^ sw));
            acc1 = MFMA32(k1, qf[ks], acc1, 0, 0, 0);
        }
        __builtin_amdgcn_s_setprio(0);

        // in-lane softmax (exp2 domain, no max, no mask) + pack P pairs to bf16
        unsigned pk0[8], pk1[8];
#pragma unroll
        for (int u = 0; u < 4; ++u) {
            float p0 = __builtin_amdgcn_exp2f(acc0[4*u+0]);
            float p1 = __builtin_amdgcn_exp2f(acc0[4*u+1]);
            float p2 = __builtin_amdgcn_exp2f(acc0[4*u+2]);
            float p3 = __builtin_amdgcn_exp2f(acc0[4*u+3]);
            lsum += (p0 + p1) + (p2 + p3);
            asm("v_cvt_pk_bf16_f32 %0, %1, %2" : "=v"(pk0[2*u+0]) : "v"(p0), "v"(p1));
            asm("v_cvt_pk_bf16_f32 %0, %1, %2" : "=v"(pk0[2*u+1]) : "v"(p2), "v"(p3));
            float s0 = __builtin_amdgcn_exp2f(acc1[4*u+0]);
            float s1 = __builtin_amdgcn_exp2f(acc1[4*u+1]);
            float s2 = __builtin_amdgcn_exp2f(acc1[4*u+2]);
            float s3 = __builtin_amdgcn_exp2f(acc1[4*u+3]);
            lsum += (s0 + s1) + (s2 + s3);
            asm("v_cvt_pk_bf16_f32 %0, %1, %2" : "=v"(pk1[2*u+0]) : "v"(s0), "v"(s1));
            asm("v_cvt_pk_bf16_f32 %0, %1, %2" : "=v"(pk1[2*u+1]) : "v"(s2), "v"(s3));
        }

        // PV: B-frag[s] built from pk via permlane32_swap; A = V^T from LDS
        const char* Vbase = (const char*)&Vlds[buf][0];
#define PV_STEP(S, PK) do {                                                         \
            unsigned a0 = PK[2 * (2 * ((S) & 1) + 0) + 0];                          \
            unsigned a1 = PK[2 * (2 * ((S) & 1) + 0) + 1];                          \
            unsigned b0 = PK[2 * (2 * ((S) & 1) + 1) + 0];                          \
            unsigned b1 = PK[2 * (2 * ((S) & 1) + 1) + 1];                          \
            asm("v_permlane32_swap_b32 %0, %1" : "+v"(a0), "+v"(b0));               \
            asm("v_permlane32_swap_b32 %0, %1" : "+v"(a1), "+v"(b1));               \
            const u32x4 fw = {a0, a1, b0, b1};                                      \
            const bf16x8 pf = __builtin_bit_cast(bf16x8, fw);                       \
            const bf16x8 v0 = *(const bf16x8*)(Vbase + c5 * 128 + (((S) * 32 + hi * 16) ^ sw)); \
            oacc0 = MFMA32(v0, pf, oacc0, 0, 0, 0);                                 \
            const bf16x8 v1 = *(const bf16x8*)(Vbase + (32 + c5) * 128 + (((S) * 32 + hi * 16) ^ sw)); \
            oacc1 = MFMA32(v1, pf, oacc1, 0, 0, 0);                                 \
        } while (0)
        __builtin_amdgcn_s_setprio(1);
        PV_STEP(0, pk0);
        PV_STEP(1, pk0);
        PV_STEP(2, pk1);
        PV_STEP(3, pk1);
        __builtin_amdgcn_s_setprio(0);
#undef PV_STEP
    }

    // epilogue: combine hi-halves, subtract masked count, divide, store O^T[dh][q]
    lsum += __shfl_xor(lsum, 32);
    lsum -= fnmask;
    const float rinv = __builtin_amdgcn_rcpf(lsum);
    float* ob = out + (size_t)(b * Dm + h * DHd) * Ls + q;
#pragma unroll
    for (int reg = 0; reg < 16; ++reg) {
        const int dh = (reg & 3) + 8 * (reg >> 2) + 4 * hi;
        ob[(size_t)dh * Ls] = oacc0[reg] * rinv;
    }
#pragma unroll
    for (int reg = 0; reg < 16; ++reg) {
        const int dh = 32 + (reg & 3) + 8 * (reg >> 2) + 4 * hi;
        ob[(size_t)dh * Ls] = oacc1[reg] * rinv;
    }
#undef STAGE
}

extern "C" void kernel_launch(void* const* d_in, const int* in_sizes, int n_in,
                              void* d_out, int out_size, void* d_ws, size_t ws_size,
                              hipStream_t stream) {
    const float* queries = (const float*)d_in[0];
    const int*   mask    = (const int*)d_in[1];
    const float* w_mem   = (const float*)d_in[2];
    const float* w_q     = (const float*)d_in[3];
    float* out = (float*)d_out;

    char* ws = (char*)d_ws;
    // layout: X 16 MB | W 1.5 MB | Q 16 MB | K 16 MB | VT 16 MB  (~69 MB)
    unsigned short* X  = (unsigned short*)(ws);
    unsigned short* W  = (unsigned short*)(ws + 16777216);
    unsigned short* Qb = (unsigned short*)(ws + 18350080);
    unsigned short* Kb = (unsigned short*)(ws + 35127296);
    unsigned short* VT = (unsigned short*)(ws + 51904512);
    if (ws_size < 68681728) return;  // fail loudly (output stays poisoned)

    pack_xw<<<dim3(2816), dim3(256), 0, stream>>>(queries, w_mem, w_q, X, W);
    gemm_qkv<<<dim3(768), dim3(512), 0, stream>>>(X, W, mask, Qb, Kb, VT);
    attn<<<dim3(512), dim3(512), 0, stream>>>(Qb, Kb, VT, mask, out);
}

// Round 14
// 88.164 us; speedup vs baseline: 1.1118x; 1.0338x over previous
//
#include <hip/hip_runtime.h>
#include <hip/hip_bf16.h>
#include <stdint.h>

#define Bsz 16
#define NHn 8
#define Dm  512
#define DHd 64
#define Ls  1024
// M = Bsz*Ls = 16384, N3 = 1536, K = 512

typedef __attribute__((ext_vector_type(8))) short bf16x8;
typedef __attribute__((ext_vector_type(4))) float f32x4;
typedef __attribute__((ext_vector_type(16))) float f32x16;
typedef __attribute__((ext_vector_type(4))) unsigned int u32x4;

#define MFMA16 __builtin_amdgcn_mfma_f32_16x16x32_bf16
#define MFMA32 __builtin_amdgcn_mfma_f32_32x32x16_bf16

// 0.125 (DH^-0.5) * log2(e): QK^T logits land pre-scaled for exp2
#define QSCALE 0.18033688011112042f

static __device__ __forceinline__ unsigned short f2bf(float f) {
    unsigned int u = __builtin_bit_cast(unsigned int, f);
    u += 0x7FFFu + ((u >> 16) & 1u);
    return (unsigned short)(u >> 16);
}

static __device__ __forceinline__ void gl2lds16(const void* g, void* l) {
    __builtin_amdgcn_global_load_lds(
        (const __attribute__((address_space(1))) unsigned int*)g,
        (__attribute__((address_space(3))) unsigned int*)l, 16, 0, 0);
}

// ------- pack_xw: fused pack_x (blocks 0..2047) + pack_w (blocks 2048..2815) -------
__global__ void __launch_bounds__(256) pack_xw(const float* __restrict__ q,
                                               const float* __restrict__ wm,
                                               const float* __restrict__ wq,
                                               unsigned short* __restrict__ X,
                                               unsigned short* __restrict__ W) {
    __shared__ float tile[64][68];
    const int t = threadIdx.x;
    if (blockIdx.x < 2048) {
        // pack_x: queries [B, D, L] f32 -> X [B*L, 512] bf16
        const int bid = blockIdx.x;
        const int b  = bid >> 7;
        const int dt = (bid >> 4) & 7;
        const int lt = bid & 15;
        const int tr = t >> 4;
        const int tc = (t & 15) * 4;
        const float* src = q + ((size_t)b * Dm + dt * 64) * Ls + lt * 64;
#pragma unroll
        for (int p = 0; p < 4; ++p) {
            const int r = p * 16 + tr;
            const float4 v = *(const float4*)(src + (size_t)r * Ls + tc);
            tile[r][tc+0] = v.x; tile[r][tc+1] = v.y; tile[r][tc+2] = v.z; tile[r][tc+3] = v.w;
        }
        __syncthreads();
        unsigned short* dst = X + (size_t)(b * Ls + lt * 64) * Dm + dt * 64;
#pragma unroll
        for (int p = 0; p < 4; ++p) {
            const int lr = p * 16 + tr;
            ushort4 o;
            o.x = f2bf(tile[tc+0][lr]);
            o.y = f2bf(tile[tc+1][lr]);
            o.z = f2bf(tile[tc+2][lr]);
            o.w = f2bf(tile[tc+3][lr]);
            *(ushort4*)(dst + (size_t)lr * Dm + tc) = o;
        }
    } else {
        // pack_w: [w_q ; w_mem] -> W [1536, 512] bf16
        const int i = ((blockIdx.x - 2048) * 256 + t) * 4;   // 1536*512 elems
        const int n = i >> 9;
        const int k = i & 511;
        const float* src = (n < 512) ? (wq + (size_t)n * 512 + k)
                                     : (wm + (size_t)(n - 512) * 512 + k);
        const float4 v = *(const float4*)src;
        ushort4 o;
        o.x = f2bf(v.x); o.y = f2bf(v.y); o.z = f2bf(v.z); o.w = f2bf(v.w);
        *(ushort4*)(W + i) = o;
    }
}

// ---------------- gemm_qkv: [16384 x 1536] = X[16384,512] * W^T ----------------
// R11-verified EXACTLY: 512-thread / 8-wave 128x128x64 dbuf template (wave grid
// 4x2, per-wave 32x64, counted vmcnt(4)), one output tile per block. T2 swizzle,
// XCD-chunked bid swizzle. Masked kv rows are ZEROED in K and V so attn needs no
// mask logic (masked p = 2^0 = 1, corrected in the denominator).
__global__ void __launch_bounds__(512) gemm_qkv(const unsigned short* __restrict__ X,
                                                const unsigned short* __restrict__ W,
                                                const int* __restrict__ mask,
                                                unsigned short* __restrict__ Qb,
                                                unsigned short* __restrict__ Kb,
                                                unsigned short* __restrict__ VT) {
    __shared__ unsigned short Alds[2][128 * 64];
    __shared__ unsigned short Blds[2][128 * 64];
    // XCD swizzle: 1536 blocks % 8 == 0 -> each XCD gets 192 contiguous (16 mt x 12 nt)
    const int bid = (blockIdx.x & 7) * 192 + (blockIdx.x >> 3);
    const int nt = bid % 12, mt = bid / 12;
    const int m0 = mt * 128, n0 = nt * 128;
    const int t = threadIdx.x;
    const int w = t >> 6, lane = t & 63, g = lane >> 4, c = lane & 15;
    const int wm = w >> 1, wn = w & 1;                   // 4 x 2 wave grid

    // staging: A/B tiles are 1024 16B chunks each; thread t stages chunks t and
    // t+512 of each. chunk ci: row = ci>>3, pc = ci&7; source col chunk pre-
    // swizzled pc ^ (row&7) (rows 64 apart share row&7, so one scol serves both).
    const int srow = t >> 3;
    const int scol = (((t & 7) ^ (srow & 7))) * 8;       // in elements

    f32x4 acc[2][4];
#pragma unroll
    for (int i = 0; i < 2; ++i)
#pragma unroll
        for (int j = 0; j < 4; ++j) acc[i][j] = f32x4{0.f, 0.f, 0.f, 0.f};

#define STAGE(BUF, KT) do {                                                      \
        const int k0_ = (KT) * 64;                                               \
        gl2lds16(X + (size_t)(m0 + srow) * Dm + k0_ + scol,                      \
                 &Alds[BUF][w * 512]);                                           \
        gl2lds16(X + (size_t)(m0 + 64 + srow) * Dm + k0_ + scol,                 \
                 &Alds[BUF][4096 + w * 512]);                                    \
        gl2lds16(W + (size_t)(n0 + srow) * Dm + k0_ + scol,                      \
                 &Blds[BUF][w * 512]);                                           \
        gl2lds16(W + (size_t)(n0 + 64 + srow) * Dm + k0_ + scol,                 \
                 &Blds[BUF][4096 + w * 512]);                                    \
    } while (0)

#define KLOOP(SWAPPED) do {                                                      \
    for (int kt = 0; kt < 8; ++kt) {                                             \
        const int buf = kt & 1;                                                  \
        if (kt < 7) {                                                            \
            STAGE(buf ^ 1, kt + 1);                                              \
            asm volatile("s_waitcnt vmcnt(4)" ::: "memory");                     \
        } else {                                                                 \
            asm volatile("s_waitcnt vmcnt(0)" ::: "memory");                     \
        }                                                                        \
        __syncthreads();                                                         \
        const char* Ab = (const char*)&Alds[buf][0];                             \
        const char* Bb = (const char*)&Blds[buf][0];                             \
        _Pragma("unroll")                                                        \
        for (int kk = 0; kk < 2; ++kk) {                                         \
            bf16x8 av[2], bv[4];                                                 \
            _Pragma("unroll")                                                    \
            for (int mi = 0; mi < 2; ++mi) {                                     \
                const int R = wm * 32 + mi * 16 + c;                             \
                av[mi] = *(const bf16x8*)(Ab + R * 128 +                         \
                          ((kk * 64 + g * 16) ^ ((R & 7) << 4)));                \
            }                                                                    \
            _Pragma("unroll")                                                    \
            for (int nj = 0; nj < 4; ++nj) {                                     \
                const int R = wn * 64 + nj * 16 + c;                             \
                bv[nj] = *(const bf16x8*)(Bb + R * 128 +                         \
                          ((kk * 64 + g * 16) ^ ((R & 7) << 4)));                \
            }                                                                    \
            _Pragma("unroll")                                                    \
            for (int mi = 0; mi < 2; ++mi)                                       \
                _Pragma("unroll")                                                \
                for (int nj = 0; nj < 4; ++nj)                                   \
                    acc[mi][nj] = (SWAPPED)                                      \
                        ? MFMA16(bv[nj], av[mi], acc[mi][nj], 0, 0, 0)           \
                        : MFMA16(av[mi], bv[nj], acc[mi][nj], 0, 0, 0);          \
        }                                                                        \
        __syncthreads();                                                         \
    }                                                                            \
} while (0)

    STAGE(0, 0);
    const int bq = m0 >> 10;                       // tiles don't straddle batches

    if (n0 < 1024) {                               // Q or K: swapped operands
        KLOOP(1);
        // C rows = n (g*4+r), cols = m (c): all 4 regs share one l
        const int m_loc = (m0 & 1023) + wm * 32 + c;
        const int hbase = ((n0 < 512) ? n0 : (n0 - 512)) >> 6;
        const bool isK = (n0 >= 512);
        unsigned short* dstbase = isK ? Kb : Qb;
        const float scale = isK ? 1.0f : QSCALE;
        unsigned short* base = dstbase + ((size_t)(bq * NHn + hbase + wn) * Ls) * DHd;
        const int dh0 = g * 4;
        int mk[2];
#pragma unroll
        for (int mi = 0; mi < 2; ++mi)
            mk[mi] = isK ? mask[bq * Ls + m_loc + mi * 16] : 1;
#pragma unroll
        for (int nj = 0; nj < 4; ++nj) {
#pragma unroll
            for (int mi = 0; mi < 2; ++mi) {
                ushort4 o;
                if (mk[mi]) {
                    o.x = f2bf(acc[mi][nj][0] * scale);
                    o.y = f2bf(acc[mi][nj][1] * scale);
                    o.z = f2bf(acc[mi][nj][2] * scale);
                    o.w = f2bf(acc[mi][nj][3] * scale);
                } else {
                    o.x = 0; o.y = 0; o.z = 0; o.w = 0;
                }
                *(ushort4*)(base + (size_t)(m_loc + mi * 16) * DHd + nj * 16 + dh0) = o;
            }
        }
    } else {                                       // V: natural operands, VT layout
        KLOOP(0);
        // C rows = m (g*4+r), cols = n (c): store 4 consecutive l
        const int m_loc = (m0 & 1023) + wm * 32 + g * 4;
        const int hbase = (n0 - 1024) >> 6;
        unsigned short* base = VT + ((size_t)(bq * NHn + hbase + wn) * DHd) * Ls;
        int4 mv[2];
#pragma unroll
        for (int mi = 0; mi < 2; ++mi)
            mv[mi] = *(const int4*)(mask + bq * Ls + m_loc + mi * 16);
#pragma unroll
        for (int nj = 0; nj < 4; ++nj) {
            const int dh = nj * 16 + c;
#pragma unroll
            for (int mi = 0; mi < 2; ++mi) {
                ushort4 o;
                o.x = mv[mi].x ? f2bf(acc[mi][nj][0]) : (unsigned short)0;
                o.y = mv[mi].y ? f2bf(acc[mi][nj][1]) : (unsigned short)0;
                o.z = mv[mi].z ? f2bf(acc[mi][nj][2]) : (unsigned short)0;
                o.w = mv[mi].w ? f2bf(acc[mi][nj][3]) : (unsigned short)0;
                *(ushort4*)(base + (size_t)dh * Ls + m_loc + mi * 16) = o;
            }
        }
    }
#undef KLOOP
#undef STAGE
}

// ---------------- attn: flash, 8 waves x 32 q-rows (QBLK=256), 32x32 MFMA ----------------
// Verified R9/R11 skeleton EXACTLY (2 buffers, 64-kv tiles, vmcnt(0), STAGE after
// barrier) + s_setprio hints around the MFMA clusters. S^T = mfma32(K, Q);
// softmax in-lane, exp2-domain, no max tracking; mask pre-folded into K/V
// (zeroed rows): masked p = 1, corrected by lsum -= nmask. P transposed via
// cvt_pk_bf16 + permlane32_swap.
__global__ void __launch_bounds__(512) attn(const unsigned short* __restrict__ Qb,
                                            const unsigned short* __restrict__ Kb,
                                            const unsigned short* __restrict__ VT,
                                            const int* __restrict__ mask,
                                            float* __restrict__ out) {
    __shared__ unsigned short Klds[2][4096];   // [64 kv][64 dh] bf16, chunk-swizzled
    __shared__ unsigned short Vlds[2][4096];   // [64 dh][64 kv] bf16, chunk-swizzled

    const int bid = blockIdx.x;
    // XCD-aware swizzle: 4 q-blocks of one bh land on one XCD (512 % 8 == 0)
    const int xcd = bid & 7;
    const int idx = bid >> 3;
    const int qblk = idx & 3;
    const int bh = ((idx >> 2) << 3) | xcd;
    const int b = bh >> 3, h = bh & 7;
    const int t = threadIdx.x, w = t >> 6, lane = t & 63;
    const int c5 = lane & 31, hi = lane >> 5;
    const int sw = (c5 & 7) << 4;

    const unsigned short* Qh = Qb + (size_t)bh * (Ls * DHd);
    const unsigned short* Kh = Kb + (size_t)bh * (Ls * DHd);
    const unsigned short* Vh = VT + (size_t)bh * (DHd * Ls);
    const int q = qblk * 256 + w * 32 + c5;

    // per-wave masked-count (one-time): lsum correction for p=1 at masked kv
    float fnmask;
    {
        int s = 0;
        const int4* mp = (const int4*)(mask + b * Ls);
#pragma unroll
        for (int j = 0; j < 4; ++j) {
            const int4 mv = mp[j * 64 + lane];
            s += (mv.x + mv.y) + (mv.z + mv.w);
        }
#pragma unroll
        for (int off = 1; off < 64; off <<= 1) s += __shfl_xor(s, off);
        fnmask = (float)(Ls - s);                  // number of masked positions
    }

    // Q fragments (B-operand of mfma32: lane holds Q[q=c5][dh = 16ks + 8hi + j])
    bf16x8 qf[4];
#pragma unroll
    for (int ks = 0; ks < 4; ++ks)
        qf[ks] = *(const bf16x8*)(Qh + (size_t)q * DHd + ks * 16 + hi * 8);

    // staging: 512 16B chunks per tile per matrix; thread t handles chunk t.
    // LDS linear dest (global_load_lds), global source pre-swizzled (rule 21).
    const int r0 = t >> 3, c0b = (t & 7) << 4;
    const int ksrc0 = r0 * 128  + (c0b ^ ((r0 & 7) << 4));
    const int vsrc0 = r0 * 2048 + (c0b ^ ((r0 & 7) << 4));

#define STAGE(BUF, KV0) do {                                          \
        const char* Kc = (const char*)Kh + (size_t)(KV0) * 128;       \
        const char* Vc = (const char*)Vh + (size_t)(KV0) * 2;         \
        gl2lds16(Kc + ksrc0, &Klds[BUF][w * 512]);                    \
        gl2lds16(Vc + vsrc0, &Vlds[BUF][w * 512]);                    \
    } while (0)

    STAGE(0, 0);

    float lsum = 0.f;
    f32x16 oacc0, oacc1;
#pragma unroll
    for (int i = 0; i < 16; ++i) { oacc0[i] = 0.f; oacc1[i] = 0.f; }

    for (int it = 0; it < 16; ++it) {
        const int kv0 = it * 64;
        const int buf = it & 1;
        asm volatile("s_waitcnt vmcnt(0)" ::: "memory");
        __syncthreads();
        if (it < 15) STAGE(buf ^ 1, kv0 + 64);

        f32x16 acc0, acc1;
#pragma unroll
        for (int i = 0; i < 16; ++i) { acc0[i] = 0.f; acc1[i] = 0.f; }

        // S^T = K * Q^T : A = K[kv row][dh k], B = Q (in reg)
        const char* Kbase = (const char*)&Klds[buf][0];
        __builtin_amdgcn_s_setprio(1);
#pragma unroll
        for (int ks = 0; ks < 4; ++ks) {
            const bf16x8 k0 = *(const bf16x8*)(Kbase + c5 * 128 + ((ks * 32 + hi * 16) ^ sw));
            acc0 = MFMA32(k0, qf[ks], acc0, 0, 0, 0);
            const bf16x8 k1 = *(const bf16x8*)(Kbase + (32 + c5) * 128 + ((ks * 32 + hi * 16) ^ sw));
            acc1 = MFMA32(k1, qf[ks], acc1, 0, 0, 0);
        }
        __builtin_amdgcn_s_setprio(0);

        // in-lane softmax (exp2 domain, no max, no mask) + pack P pairs to bf16
        unsigned pk0[8], pk1[8];
#pragma unroll
        for (int u = 0; u < 4; ++u) {
            float p0 = __builtin_amdgcn_exp2f(acc0[4*u+0]);
            float p1 = __builtin_amdgcn_exp2f(acc0[4*u+1]);
            float p2 = __builtin_amdgcn_exp2f(acc0[4*u+2]);
            float p3 = __builtin_amdgcn_exp2f(acc0[4*u+3]);
            lsum += (p0 + p1) + (p2 + p3);
            asm("v_cvt_pk_bf16_f32 %0, %1, %2" : "=v"(pk0[2*u+0]) : "v"(p0), "v"(p1));
            asm("v_cvt_pk_bf16_f32 %0, %1, %2" : "=v"(pk0[2*u+1]) : "v"(p2), "v"(p3));
            float s0 = __builtin_amdgcn_exp2f(acc1[4*u+0]);
            float s1 = __builtin_amdgcn_exp2f(acc1[4*u+1]);
            float s2 = __builtin_amdgcn_exp2f(acc1[4*u+2]);
            float s3 = __builtin_amdgcn_exp2f(acc1[4*u+3]);
            lsum += (s0 + s1) + (s2 + s3);
            asm("v_cvt_pk_bf16_f32 %0, %1, %2" : "=v"(pk1[2*u+0]) : "v"(s0), "v"(s1));
            asm("v_cvt_pk_bf16_f32 %0, %1, %2" : "=v"(pk1[2*u+1]) : "v"(s2), "v"(s3));
        }

        // PV: B-frag[s] built from pk via permlane32_swap; A = V^T from LDS
        const char* Vbase = (const char*)&Vlds[buf][0];
#define PV_STEP(S, PK) do {                                                         \
            unsigned a0 = PK[2 * (2 * ((S) & 1) + 0) + 0];                          \
            unsigned a1 = PK[2 * (2 * ((S) & 1) + 0) + 1];                          \
            unsigned b0 = PK[2 * (2 * ((S) & 1) + 1) + 0];                          \
            unsigned b1 = PK[2 * (2 * ((S) & 1) + 1) + 1];                          \
            asm("v_permlane32_swap_b32 %0, %1" : "+v"(a0), "+v"(b0));               \
            asm("v_permlane32_swap_b32 %0, %1" : "+v"(a1), "+v"(b1));               \
            const u32x4 fw = {a0, a1, b0, b1};                                      \
            const bf16x8 pf = __builtin_bit_cast(bf16x8, fw);                       \
            const bf16x8 v0 = *(const bf16x8*)(Vbase + c5 * 128 + (((S) * 32 + hi * 16) ^ sw)); \
            oacc0 = MFMA32(v0, pf, oacc0, 0, 0, 0);                                 \
            const bf16x8 v1 = *(const bf16x8*)(Vbase + (32 + c5) * 128 + (((S) * 32 + hi * 16) ^ sw)); \
            oacc1 = MFMA32(v1, pf, oacc1, 0, 0, 0);                                 \
        } while (0)
        __builtin_amdgcn_s_setprio(1);
        PV_STEP(0, pk0);
        PV_STEP(1, pk0);
        PV_STEP(2, pk1);
        PV_STEP(3, pk1);
        __builtin_amdgcn_s_setprio(0);
#undef PV_STEP
    }

    // epilogue: combine hi-halves, subtract masked count, divide, store O^T[dh][q]
    lsum += __shfl_xor(lsum, 32);
    lsum -= fnmask;
    const float rinv = __builtin_amdgcn_rcpf(lsum);
    float* ob = out + (size_t)(b * Dm + h * DHd) * Ls + q;
#pragma unroll
    for (int reg = 0; reg < 16; ++reg) {
        const int dh = (reg & 3) + 8 * (reg >> 2) + 4 * hi;
        ob[(size_t)dh * Ls] = oacc0[reg] * rinv;
    }
#pragma unroll
    for (int reg = 0; reg < 16; ++reg) {
        const int dh = 32 + (reg & 3) + 8 * (reg >> 2) + 4 * hi;
        ob[(size_t)dh * Ls] = oacc1[reg] * rinv;
    }
#undef STAGE
}

extern "C" void kernel_launch(void* const* d_in, const int* in_sizes, int n_in,
                              void* d_out, int out_size, void* d_ws, size_t ws_size,
                              hipStream_t stream) {
    const float* queries = (const float*)d_in[0];
    const int*   mask    = (const int*)d_in[1];
    const float* w_mem   = (const float*)d_in[2];
    const float* w_q     = (const float*)d_in[3];
    float* out = (float*)d_out;

    char* ws = (char*)d_ws;
    // layout: X 16 MB | W 1.5 MB | Q 16 MB | K 16 MB | VT 16 MB  (~69 MB)
    unsigned short* X  = (unsigned short*)(ws);
    unsigned short* W  = (unsigned short*)(ws + 16777216);
    unsigned short* Qb = (unsigned short*)(ws + 18350080);
    unsigned short* Kb = (unsigned short*)(ws + 35127296);
    unsigned short* VT = (unsigned short*)(ws + 51904512);
    if (ws_size < 68681728) return;  // fail loudly (output stays poisoned)

    pack_xw<<<dim3(2816), dim3(256), 0, stream>>>(queries, w_mem, w_q, X, W);
    gemm_qkv<<<dim3(1536), dim3(512), 0, stream>>>(X, W, mask, Qb, Kb, VT);
    attn<<<dim3(512), dim3(512), 0, stream>>>(Qb, Kb, VT, mask, out);
}